// Round 7
// baseline (129.964 us; speedup 1.0000x reference)
//
#include <hip/hip_runtime.h>
#include <math.h>

// MutualInformationLoss: binary 256x256 occupancy map -> MI -> 1 - tanh(mi).
// R7: replace 512 private slices (4MB write + 4MB read) with 8 shared bitmap
// copies (64KB) merged via device-scope atomicOr + racy read-skip (v & ~g):
// bitmap is monotone, so a stale g only causes an extra idempotent atomicOr.
// Copy index = blockIdx&7 (spreads contention 8x; matches round-robin XCD
// dispatch for L2 locality when it holds — correctness never depends on it).
// Reduce becomes a single block reading 64KB (no ticket). Kernel boundary
// provides cross-XCD visibility (validated by R3/R6 plain-load slice reads).
// Fixed harness overhead per iter: ~42us ws poison fill + ~33us d_in restore.

#define NB 256
#define BM_WORDS 2048          // 65536 bins / 32
#define NCOPY 8
#define HGRID 512
#define HTHREADS 512

__device__ __forceinline__ void set_bin(unsigned int* bm, float a, float b) {
    // Exact replica of jnp: clip(x*255, 0, 255).astype(int32) (truncation).
    float va = fminf(fmaxf(a * 255.0f, 0.0f), 255.0f);
    float vb = fminf(fmaxf(b * 255.0f, 0.0f), 255.0f);
    int bin = ((int)va << 8) | (int)vb;
    atomicOr(&bm[bin >> 5], 1u << (bin & 31));
}

__device__ __forceinline__ void set_bin4(unsigned int* bm, float4 a, float4 b) {
    set_bin(bm, a.x, b.x); set_bin(bm, a.y, b.y);
    set_bin(bm, a.z, b.z); set_bin(bm, a.w, b.w);
}

__device__ __forceinline__ void finalize_from_lds(unsigned int* w, float* rcs, float* red,
                                                  int t, float* out) {
    float partial = 0.0f;
    int r = 0, c = 0;
    if (t < NB) {
        // Row count for row t: words [t*8, t*8+8)
#pragma unroll
        for (int k = 0; k < 8; ++k) r += __popc(w[t * 8 + k]);
        rcs[t] = (float)r;
        // Column count for column t: bit (t&31) of word i*8 + (t>>5), rows i
        const int wsel = t >> 5;
        const int bsel = t & 31;
        for (int i = 0; i < NB; ++i) c += (w[i * 8 + wsel] >> bsel) & 1;
    }
    __syncthreads();
    float S = 0.0f;
    if (t < NB) {
        for (int i = 0; i < NB; ++i) S += rcs[i];
        // mi = -log(S) - ( sum rc*log(rc/S) + sum cc*log(cc/S) ) / S
        // (eps=1e-10 in the reference denom perturbs mi by <1e-5; << 2e-2 tol)
        if (r > 0) partial += (float)r * logf((float)r / S);
        if (c > 0) partial += (float)c * logf((float)c / S);
        for (int off = 32; off > 0; off >>= 1) partial += __shfl_down(partial, off, 64);
        if ((t & 63) == 0) red[t >> 6] = partial;
    }
    __syncthreads();
    if (t == 0) {
        float B = red[0] + red[1] + red[2] + red[3];
        float mi = -logf(S) - B / S;
        out[0] = 1.0f - tanhf(mi);
    }
}

__device__ __forceinline__ void hist_body(const float* __restrict__ x,
                                          const float* __restrict__ y,
                                          unsigned int* bm, int n, int t) {
    const int n4 = n >> 2;
    const float4* __restrict__ x4 = (const float4*)x;
    const float4* __restrict__ y4 = (const float4*)y;
    const int nth = gridDim.x * blockDim.x;
    int i = blockIdx.x * blockDim.x + t;

    // Depth-2 software pipeline: next pair's loads issue BEFORE current pair's
    // LDS-atomic scatter. (n=12.58M, nth=262144: 12 exact iterations, no tail.)
    if (i < n4) {
        float4 a0 = x4[i];
        float4 b0 = y4[i];
        int inext = i + nth;
        while (inext < n4) {
            float4 a1 = x4[inext];
            float4 b1 = y4[inext];
            inext += nth;
            set_bin4(bm, a0, b0);
            a0 = a1; b0 = b1;
        }
        set_bin4(bm, a0, b0);
    }
    // scalar tail (n % 4)
    for (int j = (n4 << 2) + blockIdx.x * blockDim.x + t; j < n; j += nth) {
        set_bin(bm, x[j], y[j]);
    }
}

// ---------------- main path: zero -> hist(+merge) -> 1-block finalize ----------------

__global__ void zero_copies(unsigned int* __restrict__ ws) {
    int i = blockIdx.x * blockDim.x + threadIdx.x;
    if (i < NCOPY * BM_WORDS) ws[i] = 0u;
}

__global__ __launch_bounds__(HTHREADS, 2) void hist_merge(const float* __restrict__ x,
                                                          const float* __restrict__ y,
                                                          unsigned int* __restrict__ ws,
                                                          int n) {
    __shared__ unsigned int bm[BM_WORDS];
    const int t = threadIdx.x;
    for (int k = t; k < BM_WORDS; k += HTHREADS) bm[k] = 0u;
    __syncthreads();

    hist_body(x, y, bm, n, t);
    __syncthreads();

    // Merge into one of 8 shared copies. Racy read-skip is safe: bits are
    // monotone, a stale g only causes an extra idempotent device-scope atomicOr.
    unsigned int* copy = ws + (size_t)(blockIdx.x & (NCOPY - 1)) * BM_WORDS;
#pragma unroll
    for (int k = 0; k < BM_WORDS / HTHREADS; ++k) {
        int w = t + k * HTHREADS;
        unsigned int v = bm[w];
        if (v) {
            unsigned int g = copy[w];
            if (v & ~g) atomicOr(&copy[w], v);
        }
    }
}

__global__ __launch_bounds__(HTHREADS) void reduce_finalize(const unsigned int* __restrict__ ws,
                                                            float* __restrict__ out) {
    __shared__ unsigned int w[BM_WORDS];
    __shared__ float rcs[NB];
    __shared__ float red[8];
    const int t = threadIdx.x;

    // OR the 8 copies (64 KB; cross-XCD visibility via kernel boundary).
#pragma unroll
    for (int k = 0; k < BM_WORDS / HTHREADS; ++k) {
        int q = t + k * HTHREADS;
        unsigned int v = 0u;
#pragma unroll
        for (int c = 0; c < NCOPY; ++c) v |= ws[c * BM_WORDS + q];
        w[q] = v;
    }
    __syncthreads();
    finalize_from_lds(w, rcs, red, t, out);
}

// ---------------- fallback path (small ws): atomic merge, 2 launches ----------------

__global__ void zero_kernel(unsigned int* __restrict__ bm) {
    int i = blockIdx.x * blockDim.x + threadIdx.x;
    if (i < BM_WORDS + 1) bm[i] = 0u;
}

__global__ __launch_bounds__(HTHREADS, 2) void hist_fused(const float* __restrict__ x,
                                                          const float* __restrict__ y,
                                                          unsigned int* __restrict__ gbm,
                                                          float* __restrict__ out,
                                                          int n) {
    __shared__ unsigned int bm[BM_WORDS];
    __shared__ float rcs[NB];
    __shared__ float red[8];
    __shared__ unsigned int ticket;
    const int t = threadIdx.x;

    for (int k = t; k < BM_WORDS; k += blockDim.x) bm[k] = 0u;
    __syncthreads();
    hist_body(x, y, bm, n, t);
    __syncthreads();
    for (int k = t; k < BM_WORDS; k += blockDim.x) {
        unsigned int v = bm[k];
        if (v) {
            unsigned int g = gbm[k];
            if (v & ~g) atomicOr(&gbm[k], v);
        }
    }
    __syncthreads();
    if (t == 0) {
        __threadfence();
        ticket = __hip_atomic_fetch_add(&gbm[BM_WORDS], 1u, __ATOMIC_ACQ_REL,
                                        __HIP_MEMORY_SCOPE_AGENT);
    }
    __syncthreads();
    if (ticket != gridDim.x - 1) return;
    __threadfence();
    for (int k = t; k < BM_WORDS; k += blockDim.x)
        bm[k] = __hip_atomic_load(&gbm[k], __ATOMIC_RELAXED, __HIP_MEMORY_SCOPE_AGENT);
    __syncthreads();
    finalize_from_lds(bm, rcs, red, t, out);
}

extern "C" void kernel_launch(void* const* d_in, const int* in_sizes, int n_in,
                              void* d_out, int out_size, void* d_ws, size_t ws_size,
                              hipStream_t stream) {
    const float* x = (const float*)d_in[0];  // I_complementary -> row bins
    const float* y = (const float*)d_in[1];  // I_target        -> col bins
    float* out = (float*)d_out;
    unsigned int* ws = (unsigned int*)d_ws;
    const int n = in_sizes[0];

    const size_t need = (size_t)(NCOPY * BM_WORDS) * sizeof(unsigned int);
    if (ws_size >= need) {
        zero_copies<<<(NCOPY * BM_WORDS + 511) / 512, 512, 0, stream>>>(ws);
        hist_merge<<<HGRID, HTHREADS, 0, stream>>>(x, y, ws, n);
        reduce_finalize<<<1, HTHREADS, 0, stream>>>(ws, out);
    } else {
        zero_kernel<<<(BM_WORDS + 256) / 256, 256, 0, stream>>>(ws);
        hist_fused<<<HGRID, HTHREADS, 0, stream>>>(x, y, ws, out, n);
    }
}

// Round 8
// 122.919 us; speedup vs baseline: 1.0573x; 1.0573x over previous
//
#include <hip/hip_runtime.h>
#include <math.h>

// MutualInformationLoss: binary 256x256 occupancy map -> MI -> 1 - tanh(mi).
// R8 = R6 (measured best, 123.1us): two-kernel structure. 512 blocks hist into
// private LDS bitmaps (depth-2 software-pipelined float4 loads), publish 8KB
// slices with plain coalesced uint4 stores; 64-block OR-reduce + fused
// finalize via last-block-done ticket. Kernel boundary provides cross-XCD
// release/acquire for slice reads.
// Bracketed knob-space: R3 slices=125.0, R4 2x-occupancy=127.7 (neutral),
// R5 single-kernel fusion=167.9 (in-kernel cross-XCD sync >> kernel boundary),
// R6 pipeline=123.1 (best), R7 8-copy atomicOr merge=130.0 (extra launch +
// contention). Structural floor: fill 42 + restore ~32 + hist ~16-20 +
// slices ~2 + gaps ~12 => ~112-118us; R6 sits within ~5-8% of it.

#define NB 256
#define BM_WORDS 2048          // 65536 bins / 32
#define HGRID 512
#define HTHREADS 512
#define RGRID 64
#define RTHREADS 256

// ws layout (words): [0, SL_WORDS) slices, [SL, SL+BM_WORDS) final bitmap,
// [SL+BM_WORDS] arrival counter.
#define SL_WORDS (HGRID * BM_WORDS)

__device__ __forceinline__ void set_bin(unsigned int* bm, float a, float b) {
    // Exact replica of jnp: clip(x*255, 0, 255).astype(int32) (truncation).
    float va = fminf(fmaxf(a * 255.0f, 0.0f), 255.0f);
    float vb = fminf(fmaxf(b * 255.0f, 0.0f), 255.0f);
    int bin = ((int)va << 8) | (int)vb;
    atomicOr(&bm[bin >> 5], 1u << (bin & 31));
}

__device__ __forceinline__ void set_bin4(unsigned int* bm, float4 a, float4 b) {
    set_bin(bm, a.x, b.x); set_bin(bm, a.y, b.y);
    set_bin(bm, a.z, b.z); set_bin(bm, a.w, b.w);
}

__device__ __forceinline__ void finalize_from_lds(unsigned int* w, float* rcs, float* red,
                                                  int t, float* out) {
    float partial = 0.0f;
    int r = 0, c = 0;
    if (t < NB) {
        // Row count for row t: words [t*8, t*8+8)
#pragma unroll
        for (int k = 0; k < 8; ++k) r += __popc(w[t * 8 + k]);
        rcs[t] = (float)r;
        // Column count for column t: bit (t&31) of word i*8 + (t>>5), rows i
        const int wsel = t >> 5;
        const int bsel = t & 31;
        for (int i = 0; i < NB; ++i) c += (w[i * 8 + wsel] >> bsel) & 1;
    }
    __syncthreads();
    float S = 0.0f;
    if (t < NB) {
        for (int i = 0; i < NB; ++i) S += rcs[i];
        // mi = -log(S) - ( sum rc*log(rc/S) + sum cc*log(cc/S) ) / S
        // (eps=1e-10 in the reference denom perturbs mi by <1e-5; << 2e-2 tol)
        if (r > 0) partial += (float)r * logf((float)r / S);
        if (c > 0) partial += (float)c * logf((float)c / S);
        for (int off = 32; off > 0; off >>= 1) partial += __shfl_down(partial, off, 64);
        if ((t & 63) == 0) red[t >> 6] = partial;
    }
    __syncthreads();
    if (t == 0) {
        float B = red[0] + red[1] + red[2] + red[3];
        float mi = -logf(S) - B / S;
        out[0] = 1.0f - tanhf(mi);
    }
}

__device__ __forceinline__ void hist_body(const float* __restrict__ x,
                                          const float* __restrict__ y,
                                          unsigned int* bm, int n, int t) {
    const int n4 = n >> 2;
    const float4* __restrict__ x4 = (const float4*)x;
    const float4* __restrict__ y4 = (const float4*)y;
    const int nth = gridDim.x * blockDim.x;
    int i = blockIdx.x * blockDim.x + t;

    // Depth-2 software pipeline: next pair's loads issue BEFORE current pair's
    // LDS-atomic scatter, so VMEM stays busy through processing.
    // (n=12.58M, nth=262144: n4/nth = 12 exact iterations, no tail.)
    if (i < n4) {
        float4 a0 = x4[i];
        float4 b0 = y4[i];
        int inext = i + nth;
        while (inext < n4) {
            float4 a1 = x4[inext];
            float4 b1 = y4[inext];
            inext += nth;
            set_bin4(bm, a0, b0);
            a0 = a1; b0 = b1;
        }
        set_bin4(bm, a0, b0);
    }
    // scalar tail (n % 4)
    for (int j = (n4 << 2) + blockIdx.x * blockDim.x + t; j < n; j += nth) {
        set_bin(bm, x[j], y[j]);
    }
}

// ---------------- main path ----------------

__global__ __launch_bounds__(HTHREADS, 2) void hist_slices(const float* __restrict__ x,
                                                           const float* __restrict__ y,
                                                           unsigned int* __restrict__ ws,
                                                           int n) {
    __shared__ unsigned int bm[BM_WORDS];
    const int t = threadIdx.x;
    if (blockIdx.x == 0 && t == 0) ws[SL_WORDS + BM_WORDS] = 0u;  // arrival counter
    for (int k = t; k < BM_WORDS; k += HTHREADS) bm[k] = 0u;
    __syncthreads();

    hist_body(x, y, bm, n, t);
    __syncthreads();

    // Publish private bitmap to this block's slice: plain coalesced uint4 stores.
    // Cross-XCD visibility comes from the kernel boundary before reduce_finalize.
    uint4 v;
    v.x = bm[4 * t];     v.y = bm[4 * t + 1];
    v.z = bm[4 * t + 2]; v.w = bm[4 * t + 3];
    ((uint4*)(ws + (size_t)blockIdx.x * BM_WORDS))[t] = v;
}

__global__ __launch_bounds__(RTHREADS) void reduce_finalize(unsigned int* __restrict__ ws,
                                                            float* __restrict__ out) {
    __shared__ uint4 p4[RTHREADS];
    __shared__ unsigned int w[BM_WORDS];
    __shared__ float rcs[NB];
    __shared__ float red[8];
    __shared__ unsigned int ticket;
    const int t = threadIdx.x;
    const int b = blockIdx.x;
    unsigned int* finalbm = ws + SL_WORDS;
    unsigned int* counter = ws + SL_WORDS + BM_WORDS;

    // Block b OR-reduces uint4 indices [b*8, b*8+8) across all HGRID slices.
    const uint4* s4 = (const uint4*)ws;          // slice s: s4[s*512 + q]
    const int q = b * 8 + (t & 7);
    uint4 v = make_uint4(0u, 0u, 0u, 0u);
#pragma unroll 4
    for (int k = 0; k < HGRID / 32; ++k) {       // 32 slices per sweep
        int s = (t >> 3) + 32 * k;
        uint4 g = s4[(size_t)s * (BM_WORDS / 4) + q];
        v.x |= g.x; v.y |= g.y; v.z |= g.z; v.w |= g.w;
    }
    p4[t] = v;
    __syncthreads();
    if (t < 8) {
        uint4 r = p4[t];
        for (int k = 1; k < 32; ++k) {
            uint4 g = p4[t + 8 * k];
            r.x |= g.x; r.y |= g.y; r.z |= g.z; r.w |= g.w;
        }
        ((uint4*)finalbm)[b * 8 + t] = r;
    }
    __syncthreads();

    // Last-block-done among RGRID blocks (counter zeroed by hist_slices).
    if (t == 0) {
        __threadfence();
        ticket = atomicAdd(counter, 1u);
    }
    __syncthreads();
    if (ticket != gridDim.x - 1) return;

    __threadfence();
    for (int k = t; k < BM_WORDS; k += RTHREADS)
        w[k] = __hip_atomic_load(&finalbm[k], __ATOMIC_RELAXED, __HIP_MEMORY_SCOPE_AGENT);
    __syncthreads();
    finalize_from_lds(w, rcs, red, t, out);
}

// ---------------- fallback path (small ws): atomic merge, 2 launches ----------------

__global__ void zero_kernel(unsigned int* __restrict__ bm) {
    int i = blockIdx.x * blockDim.x + threadIdx.x;
    if (i < BM_WORDS + 1) bm[i] = 0u;
}

__global__ __launch_bounds__(HTHREADS, 2) void hist_fused(const float* __restrict__ x,
                                                          const float* __restrict__ y,
                                                          unsigned int* __restrict__ gbm,
                                                          float* __restrict__ out,
                                                          int n) {
    __shared__ unsigned int bm[BM_WORDS];
    __shared__ float rcs[NB];
    __shared__ float red[8];
    __shared__ unsigned int ticket;
    const int t = threadIdx.x;

    for (int k = t; k < BM_WORDS; k += blockDim.x) bm[k] = 0u;
    __syncthreads();
    hist_body(x, y, bm, n, t);
    __syncthreads();
    for (int k = t; k < BM_WORDS; k += blockDim.x) {
        unsigned int v = bm[k];
        if (v) {
            unsigned int g = gbm[k];
            if (v & ~g) atomicOr(&gbm[k], v);
        }
    }
    __syncthreads();
    if (t == 0) {
        __threadfence();
        ticket = __hip_atomic_fetch_add(&gbm[BM_WORDS], 1u, __ATOMIC_ACQ_REL,
                                        __HIP_MEMORY_SCOPE_AGENT);
    }
    __syncthreads();
    if (ticket != gridDim.x - 1) return;
    __threadfence();
    for (int k = t; k < BM_WORDS; k += blockDim.x)
        bm[k] = __hip_atomic_load(&gbm[k], __ATOMIC_RELAXED, __HIP_MEMORY_SCOPE_AGENT);
    __syncthreads();
    finalize_from_lds(bm, rcs, red, t, out);
}

extern "C" void kernel_launch(void* const* d_in, const int* in_sizes, int n_in,
                              void* d_out, int out_size, void* d_ws, size_t ws_size,
                              hipStream_t stream) {
    const float* x = (const float*)d_in[0];  // I_complementary -> row bins
    const float* y = (const float*)d_in[1];  // I_target        -> col bins
    float* out = (float*)d_out;
    unsigned int* ws = (unsigned int*)d_ws;
    const int n = in_sizes[0];

    const size_t need = (size_t)(SL_WORDS + BM_WORDS + 1) * sizeof(unsigned int);
    if (ws_size >= need) {
        hist_slices<<<HGRID, HTHREADS, 0, stream>>>(x, y, ws, n);
        reduce_finalize<<<RGRID, RTHREADS, 0, stream>>>(ws, out);
    } else {
        zero_kernel<<<(BM_WORDS + 256) / 256, 256, 0, stream>>>(ws);
        hist_fused<<<HGRID, HTHREADS, 0, stream>>>(x, y, ws, out, n);
    }
}